// Round 1
// baseline (295.762 us; speedup 1.0000x reference)
//
#include <hip/hip_runtime.h>

#define ISZ 10
#define HSZ 20
#define BSZ 4096
#define TSZ 512
#define BPW 3                          // batches per wave (20 lanes each, 4 idle)
#define NBLK ((BSZ + BPW - 1) / BPW)   // 1366 one-wave blocks

__device__ __forceinline__ float fsig(float x) {
    // sigmoid(x) = 1/(1+2^(-x*log2e))
    return __builtin_amdgcn_rcpf(1.0f + __builtin_amdgcn_exp2f(-1.44269504f * x));
}
__device__ __forceinline__ float ftanh(float x) {
    // tanh(x) = 1 - 2/(2^(2x*log2e)+1); saturates correctly via inf/0
    return 1.0f - 2.0f * __builtin_amdgcn_rcpf(1.0f + __builtin_amdgcn_exp2f(2.88539008f * x));
}

__global__ __launch_bounds__(64) void lstm_fwd(
    const float* __restrict__ data, const float* __restrict__ Wih,
    const float* __restrict__ Whh, const float* __restrict__ bih,
    const float* __restrict__ bhh, float* __restrict__ partials)
{
    // 4 h-rows: groups 0..2 are real batches, row 3 is trash for idle lanes
    __shared__ __align__(16) float hbuf[4 * HSZ];

    const int lane  = threadIdx.x;        // 0..63
    const int g     = lane / HSZ;         // batch group 0..3 (3 = idle lanes)
    const int j     = lane - g * HSZ;     // hidden unit 0..19
    const int batch = blockIdx.x * BPW + g;
    const bool active = (g < BPW) && (batch < BSZ);
    const int bl = active ? batch : 0;    // clamp for safe loads

    // Per-thread weight rows in registers: gate order i,f,g,o (rows j, j+20, j+40, j+60)
    float wih[4][ISZ], whh[4][HSZ], bias[4];
#pragma unroll
    for (int q = 0; q < 4; ++q) {
        const int row = q * HSZ + j;
#pragma unroll
        for (int i = 0; i < ISZ; ++i) wih[q][i] = Wih[row * ISZ + i];
#pragma unroll
        for (int k = 0; k < HSZ; ++k) whh[q][k] = Whh[row * HSZ + k];
        bias[q] = bih[row] + bhh[row];
    }

    float* hrow = &hbuf[g * HSZ];
    hrow[j] = 0.0f;
    if (g == 3) {  // zero the rest of the trash row (only j=0..3 exist there)
        hrow[j + 4] = 0.0f; hrow[j + 8] = 0.0f; hrow[j + 12] = 0.0f; hrow[j + 16] = 0.0f;
    }
    asm volatile("" ::: "memory");

    float c = 0.0f, sum = 0.0f;
    const float* xbase = data + (size_t)bl * (TSZ * ISZ);

    float xa[ISZ], xb[ISZ];

    auto loadx = [&](float* dst, int t) {
        const float2* p = (const float2*)(xbase + t * ISZ);  // 8B-aligned (t*40B)
        float2 v0 = p[0], v1 = p[1], v2 = p[2], v3 = p[3], v4 = p[4];
        dst[0] = v0.x; dst[1] = v0.y; dst[2] = v1.x; dst[3] = v1.y; dst[4] = v2.x;
        dst[5] = v2.y; dst[6] = v3.x; dst[7] = v3.y; dst[8] = v4.x; dst[9] = v4.y;
    };

    auto step = [&](const float* x) {
        // read full h of my batch (written by the 20 lanes last step; wave-lockstep safe)
        float h[HSZ];
        const float4* h4 = (const float4*)hrow;
        float4 a0 = h4[0], a1 = h4[1], a2 = h4[2], a3 = h4[3], a4 = h4[4];
        h[0]=a0.x; h[1]=a0.y; h[2]=a0.z; h[3]=a0.w;
        h[4]=a1.x; h[5]=a1.y; h[6]=a1.z; h[7]=a1.w;
        h[8]=a2.x; h[9]=a2.y; h[10]=a2.z; h[11]=a2.w;
        h[12]=a3.x; h[13]=a3.y; h[14]=a3.z; h[15]=a3.w;
        h[16]=a4.x; h[17]=a4.y; h[18]=a4.z; h[19]=a4.w;

        float acc[4];
#pragma unroll
        for (int q = 0; q < 4; ++q) {
            float a = bias[q];
#pragma unroll
            for (int i = 0; i < ISZ; ++i) a += wih[q][i] * x[i];
#pragma unroll
            for (int k = 0; k < HSZ; ++k) a += whh[q][k] * h[k];
            acc[q] = a;
        }
        float ig = fsig(acc[0]);
        float fg = fsig(acc[1]);
        float gg = ftanh(acc[2]);
        float og = fsig(acc[3]);
        c = fg * c + ig * gg;
        float hn = og * ftanh(c);
        sum += hn;
        hrow[j] = hn;
        asm volatile("" ::: "memory");  // force LDS re-read next step (wave-sync idiom)
    };

    loadx(xa, 0);
    for (int t = 0; t < TSZ; t += 2) {
        loadx(xb, t + 1);                 // prefetch: latency hides under step(xa)
        step(xa);
        const int t2 = (t + 2 < TSZ) ? (t + 2) : (TSZ - 1);
        loadx(xa, t2);                    // prefetch next pair (last iter: harmless reload)
        step(xb);
    }

    if (!active) sum = 0.0f;
#pragma unroll
    for (int off = 32; off > 0; off >>= 1) sum += __shfl_down(sum, off, 64);
    if (lane == 0) partials[blockIdx.x] = sum;
}

__global__ __launch_bounds__(1024) void reduce_partials(
    const float* __restrict__ partials, float* __restrict__ out)
{
    float s = 0.0f;
    for (int i = threadIdx.x; i < NBLK; i += 1024) s += partials[i];
#pragma unroll
    for (int off = 32; off > 0; off >>= 1) s += __shfl_down(s, off, 64);
    __shared__ float wsum[16];
    const int w = threadIdx.x >> 6;
    if ((threadIdx.x & 63) == 0) wsum[w] = s;
    __syncthreads();
    if (threadIdx.x < 16) {
        float v = wsum[threadIdx.x];
#pragma unroll
        for (int off = 8; off > 0; off >>= 1) v += __shfl_down(v, off, 64);
        if (threadIdx.x == 0) out[0] = v;
    }
}

extern "C" void kernel_launch(void* const* d_in, const int* in_sizes, int n_in,
                              void* d_out, int out_size, void* d_ws, size_t ws_size,
                              hipStream_t stream) {
    const float* data = (const float*)d_in[0];
    const float* Wih  = (const float*)d_in[1];
    const float* Whh  = (const float*)d_in[2];
    const float* bih  = (const float*)d_in[3];
    const float* bhh  = (const float*)d_in[4];
    float* out        = (float*)d_out;
    float* partials   = (float*)d_ws;   // NBLK floats, fully written every launch

    lstm_fwd<<<NBLK, 64, 0, stream>>>(data, Wih, Whh, bih, bhh, partials);
    reduce_partials<<<1, 1024, 0, stream>>>(partials, out);
}

// Round 3
// 223.209 us; speedup vs baseline: 1.3250x; 1.3250x over previous
//
#include <hip/hip_runtime.h>

#define ISZ 10
#define HSZ 20
#define BSZ 4096
#define TSZ 512
#define BPW 3                          // batches per wave (20 lanes each, 4 idle)
#define NBLK ((BSZ + BPW - 1) / BPW)   // 1366 one-wave blocks

typedef __fp16 half2_t __attribute__((ext_vector_type(2)));

__device__ __forceinline__ float fdot2(half2_t a, half2_t b, float c) {
    return __builtin_amdgcn_fdot2(a, b, c, false);
}

__device__ __forceinline__ float fsig(float x) {
    // sigmoid(x) = 1/(1+2^(-x*log2e))
    return __builtin_amdgcn_rcpf(1.0f + __builtin_amdgcn_exp2f(-1.44269504f * x));
}
__device__ __forceinline__ float ftanh(float x) {
    // tanh(x) = 1 - 2/(2^(2x*log2e)+1); saturates correctly via inf/0
    return 1.0f - 2.0f * __builtin_amdgcn_rcpf(1.0f + __builtin_amdgcn_exp2f(2.88539008f * x));
}

__global__ __launch_bounds__(64) void lstm_fwd(
    const float* __restrict__ data, const float* __restrict__ Wih,
    const float* __restrict__ Whh, const float* __restrict__ bih,
    const float* __restrict__ bhh, float* __restrict__ partials)
{
    // 4 h-rows (f16), stride 24 halves = 48 B so each row is 16B-aligned.
    // Groups 0..2 are real batches, row 3 is trash for the 4 idle lanes.
    __shared__ __align__(16) __fp16 hbuf[4 * 24];

    const int lane  = threadIdx.x;        // 0..63
    const int g     = lane / HSZ;         // batch group 0..3 (3 = idle lanes)
    const int j     = lane - g * HSZ;     // hidden unit 0..19
    const int batch = blockIdx.x * BPW + g;
    const bool active = (g < BPW) && (batch < BSZ);
    const int bl = active ? batch : 0;    // clamp for safe loads

    // Per-thread weight rows packed to f16 pairs (RNE via C cast).
    // Gate order i,f,g,o -> rows j, j+20, j+40, j+60.
    half2_t wih2[4][ISZ / 2], whh2[4][HSZ / 2];
    float bias[4];
#pragma unroll
    for (int q = 0; q < 4; ++q) {
        const int row = q * HSZ + j;
#pragma unroll
        for (int i = 0; i < ISZ / 2; ++i) {
            wih2[q][i].x = (__fp16)Wih[row * ISZ + 2 * i];
            wih2[q][i].y = (__fp16)Wih[row * ISZ + 2 * i + 1];
        }
#pragma unroll
        for (int k = 0; k < HSZ / 2; ++k) {
            whh2[q][k].x = (__fp16)Whh[row * HSZ + 2 * k];
            whh2[q][k].y = (__fp16)Whh[row * HSZ + 2 * k + 1];
        }
        bias[q] = bih[row] + bhh[row];
    }

    __fp16* hrow = &hbuf[g * 24];
    // zero full rows (including trash row + padding never read)
    if (j < 12) { hrow[j] = (__fp16)0.f; hrow[j + 12] = (__fp16)0.f; }
    if (g == 3) {
#pragma unroll
        for (int k = j; k < 24; k += 4) hrow[k] = (__fp16)0.f;
    }
    asm volatile("" ::: "memory");

    float c = 0.0f, sum = 0.0f;
    const float* xbase = data + (size_t)bl * (TSZ * ISZ);

    half2_t xa[ISZ / 2], xb[ISZ / 2];

    auto loadx = [&](half2_t* dst, int t) {
        const float2* p = (const float2*)(xbase + t * ISZ);  // 8B-aligned (t*40B)
        float2 v0 = p[0], v1 = p[1], v2 = p[2], v3 = p[3], v4 = p[4];
        dst[0] = __builtin_amdgcn_cvt_pkrtz(v0.x, v0.y);
        dst[1] = __builtin_amdgcn_cvt_pkrtz(v1.x, v1.y);
        dst[2] = __builtin_amdgcn_cvt_pkrtz(v2.x, v2.y);
        dst[3] = __builtin_amdgcn_cvt_pkrtz(v3.x, v3.y);
        dst[4] = __builtin_amdgcn_cvt_pkrtz(v4.x, v4.y);
    };

    auto step = [&](const half2_t* x) {
        // issue h reads first so their latency hides under the x-dots
        half2_t h2[HSZ / 2];
        const half2_t* hp = (const half2_t*)__builtin_assume_aligned(hrow, 16);
#pragma unroll
        for (int k = 0; k < HSZ / 2; ++k) h2[k] = hp[k];

        float acc[4];
#pragma unroll
        for (int q = 0; q < 4; ++q) {
            float a = bias[q];
#pragma unroll
            for (int i = 0; i < ISZ / 2; ++i) a = fdot2(wih2[q][i], x[i], a);
            acc[q] = a;
        }
#pragma unroll
        for (int q = 0; q < 4; ++q) {
            float a = acc[q];
#pragma unroll
            for (int k = 0; k < HSZ / 2; ++k) a = fdot2(whh2[q][k], h2[k], a);
            acc[q] = a;
        }
        float ig = fsig(acc[0]);
        float fg = fsig(acc[1]);
        float gg = ftanh(acc[2]);
        float og = fsig(acc[3]);
        c = fg * c + ig * gg;
        float hn = og * ftanh(c);
        sum += hn;
        hrow[j] = (__fp16)hn;
        asm volatile("" ::: "memory");  // force LDS re-read next step (wave-sync idiom)
    };

    loadx(xa, 0);
    for (int t = 0; t < TSZ; t += 2) {
        loadx(xb, t + 1);                 // prefetch: latency hides under step(xa)
        step(xa);
        const int t2 = (t + 2 < TSZ) ? (t + 2) : (TSZ - 1);
        loadx(xa, t2);                    // prefetch next pair (last iter: harmless reload)
        step(xb);
    }

    if (!active) sum = 0.0f;
#pragma unroll
    for (int off = 32; off > 0; off >>= 1) sum += __shfl_down(sum, off, 64);
    if (lane == 0) partials[blockIdx.x] = sum;
}

__global__ __launch_bounds__(1024) void reduce_partials(
    const float* __restrict__ partials, float* __restrict__ out)
{
    float s = 0.0f;
    for (int i = threadIdx.x; i < NBLK; i += 1024) s += partials[i];
#pragma unroll
    for (int off = 32; off > 0; off >>= 1) s += __shfl_down(s, off, 64);
    __shared__ float wsum[16];
    const int w = threadIdx.x >> 6;
    if ((threadIdx.x & 63) == 0) wsum[w] = s;
    __syncthreads();
    if (threadIdx.x < 16) {
        float v = wsum[threadIdx.x];
#pragma unroll
        for (int off = 8; off > 0; off >>= 1) v += __shfl_down(v, off, 64);
        if (threadIdx.x == 0) out[0] = v;
    }
}

extern "C" void kernel_launch(void* const* d_in, const int* in_sizes, int n_in,
                              void* d_out, int out_size, void* d_ws, size_t ws_size,
                              hipStream_t stream) {
    const float* data = (const float*)d_in[0];
    const float* Wih  = (const float*)d_in[1];
    const float* Whh  = (const float*)d_in[2];
    const float* bih  = (const float*)d_in[3];
    const float* bhh  = (const float*)d_in[4];
    float* out        = (float*)d_out;
    float* partials   = (float*)d_ws;   // NBLK floats, fully written every launch

    lstm_fwd<<<NBLK, 64, 0, stream>>>(data, Wih, Whh, bih, bhh, partials);
    reduce_partials<<<1, 1024, 0, stream>>>(partials, out);
}